// Round 2
// baseline (799.087 us; speedup 1.0000x reference)
//
#include <hip/hip_runtime.h>
#include <math.h>

// Problem constants
#define BB   64
#define CIN  16
#define LL   8192
#define CO   32
#define TCO  64
constexpr int T0n = 128;   // frames for n=64
constexpr int T1n = 32;    // frames for n=256
constexpr int F0n = 33;
constexpr int F1n = 129;

// ---------------- STFT: real-input DFT, k<->n-k pairing, rotation recurrence ----
// p layout: [b][t][c][f] (float2 = re,im)
template<int N, int F, int TCH, int TFR>
__global__ __launch_bounds__(256)
void stft_kernel(const float* __restrict__ x, float2* __restrict__ p) {
    constexpr int NCH  = TFR / TCH;
    constexpr int SPAN = N * TCH;          // 512 for both configs
    static_assert(SPAN == 512, "span");
    __shared__ float  xs[SPAN];
    __shared__ float2 uv[TCH][N / 2];      // (u,v), k=1..N/2-1
    __shared__ float2 edge[TCH];           // (x[0], x[N/2])
    int bid   = blockIdx.x;
    int chunk = bid % NCH;
    int bc    = bid / NCH;                 // b*CIN + c
    const float* xrow = x + (size_t)bc * LL;
    int g0 = chunk * SPAN - N / 2;
    for (int i = threadIdx.x; i < SPAN; i += 256) {
        int gi = g0 + i; gi = gi < 0 ? -gi : gi;   // reflect (left edge only)
        xs[i] = xrow[gi];
    }
    __syncthreads();
    for (int i = threadIdx.x; i < TCH * (N / 2); i += 256) {
        int fl = i / (N / 2), k = i % (N / 2);
        float a = xs[fl * N + k];
        if (k == 0) {
            edge[fl] = make_float2(a, xs[fl * N + N / 2]);
        } else {
            float b2 = xs[fl * N + N - k];
            uv[fl][k] = make_float2(a + b2, a - b2);
        }
    }
    __syncthreads();
    int c = bc % CIN, b = bc / CIN;
    for (int j = threadIdx.x; j < TCH * F; j += 256) {
        int fl = j / F, f = j - fl * F;
        float2 e = edge[fl];
        float re = e.x + ((f & 1) ? -e.y : e.y);
        float im = 0.f;
        float s1, c1;
        sincosf(6.28318530717958647692f * (float)f / (float)N, &s1, &c1);
        float cc = c1, ss = s1;            // angle = 2*pi*f*k/N at k=1
        #pragma unroll 4
        for (int k = 1; k < N / 2; ++k) {
            float2 w = uv[fl][k];
            re = fmaf(w.x, cc, re);        // + u*cos
            im = fmaf(-w.y, ss, im);       // - v*sin
            float cn = fmaf(cc, c1, -ss * s1);
            ss = fmaf(cc, s1, ss * c1);
            cc = cn;
        }
        int t = chunk * TCH + fl;
        p[(((size_t)b * TFR + t) * CIN + c) * F + f] = make_float2(re, im);
    }
}

// ---------------- merge (attention over 4 sub-frames), in-place into p1 --------
__global__ __launch_bounds__(256)
void merge_kernel(const float2* __restrict__ p0, float2* __restrict__ p1,
                  const float* __restrict__ mkr, const float* __restrict__ mki,
                  const float* __restrict__ mbr, const float* __restrict__ mbi) {
    int idx = blockIdx.x * 256 + threadIdx.x;
    const int total = BB * T1n * CIN * F0n;
    if (idx >= total) return;
    int f0 = idx % F0n; int r1 = idx / F0n;
    int c  = r1 % CIN;  int r2 = r1 / CIN;
    int t1 = r2 % T1n;  int b  = r2 / T1n;
    float2 pm[4];
    #pragma unroll
    for (int r = 0; r < 4; ++r) {
        int t = t1 * 4 + r;
        pm[r] = p0[(((size_t)b * T0n + t) * CIN + c) * F0n + f0];
    }
    float mag[4], mx = -1e30f;
    #pragma unroll
    for (int s = 0; s < 4; ++s) {
        float atr = mbr[s], ati = mbi[s];
        #pragma unroll
        for (int r = 0; r < 4; ++r) {
            float kr = mkr[r * 4 + s], ki = mki[r * 4 + s];
            atr = fmaf(pm[r].x, kr, atr); atr = fmaf(-pm[r].y, ki, atr);
            ati = fmaf(pm[r].x, ki, ati); ati = fmaf(pm[r].y, kr, ati);
        }
        mag[s] = sqrtf(atr * atr + ati * ati);
        mx = fmaxf(mx, mag[s]);
    }
    float se = 0.f;
    #pragma unroll
    for (int s = 0; s < 4; ++s) { mag[s] = expf(mag[s] - mx); se += mag[s]; }
    float inv = 4.0f / se;                 // RATIO / sum
    float mr = 0.f, mi = 0.f;
    #pragma unroll
    for (int r = 0; r < 4; ++r) { mr = fmaf(pm[r].x, mag[r], mr); mi = fmaf(pm[r].y, mag[r], mi); }
    p1[(((size_t)b * T1n + t1) * CIN + c) * F1n + 4 * f0] = make_float2(mr * inv, mi * inv);
}

// ---------------- complex batch-norm stats -> per-batch affine ------------------
__global__ __launch_bounds__(256)
void cbn_kernel(const float2* __restrict__ p0, const float2* __restrict__ p1,
                const float* __restrict__ gamma, const float* __restrict__ beta,
                float4* __restrict__ bn) {
    int head = blockIdx.x >> 6;
    int b    = blockIdx.x & 63;
    int Nel  = head ? (T1n * CIN * F1n) : (T0n * CIN * F0n);
    const float2* base = head ? (p1 + (size_t)b * (T1n * CIN * F1n))
                              : (p0 + (size_t)b * (T0n * CIN * F0n));
    float sr = 0.f, si = 0.f, s2 = 0.f;
    for (int i = threadIdx.x; i < Nel; i += 256) {
        float2 v = base[i];
        sr += v.x; si += v.y;
        s2 = fmaf(v.x, v.x, s2); s2 = fmaf(v.y, v.y, s2);
    }
    __shared__ float red[3][256];
    red[0][threadIdx.x] = sr; red[1][threadIdx.x] = si; red[2][threadIdx.x] = s2;
    __syncthreads();
    for (int off = 128; off > 0; off >>= 1) {
        if (threadIdx.x < off) {
            red[0][threadIdx.x] += red[0][threadIdx.x + off];
            red[1][threadIdx.x] += red[1][threadIdx.x + off];
            red[2][threadIdx.x] += red[2][threadIdx.x + off];
        }
        __syncthreads();
    }
    if (threadIdx.x == 0) {
        float invN = 1.f / (float)Nel;
        float mur = red[0][0] * invN, mui = red[1][0] * invN;
        float var = red[2][0] * invN - mur * mur - mui * mui;
        float g = gamma[head * BB + b] * rsqrtf(var + 1e-5f);
        bn[head * BB + b] = make_float4(g, beta[head * BB + b] - mur * g, -mui * g, 0.f);
    }
}

// ---------------- fused CBN-apply + einsum + irfft + bias/relu/store -----------
// grid: B*(TFR+1); frame TFR re-uses spectrum of frame 0 (the appended wrap frame)
template<int N, int F, int TFR, int CH0>
__global__ __launch_bounds__(256)
void istft_kernel(const float2* __restrict__ p, const float* __restrict__ fkr,
                  const float* __restrict__ fki, const float4* __restrict__ bn,
                  const float* __restrict__ pbias, float* __restrict__ out) {
    constexpr int FP = F + 1;              // even float2 row stride -> 16B aligned rows
    __shared__ float2 xbn[CIN][F];
    __shared__ __align__(16) float2 S[CO][FP];
    int t  = blockIdx.x % (TFR + 1);
    int b  = blockIdx.x / (TFR + 1);
    int tf = (t == TFR) ? 0 : t;
    float4 par = bn[(CH0 ? 1 : 0) * BB + b];   // (s, cb_re, cb_im, -)
    const float2* acc = p + ((size_t)b * TFR + tf) * CIN * F;
    for (int i = threadIdx.x; i < CIN * F; i += 256) {
        float2 v = acc[i];
        ((float2*)xbn)[i] = make_float2(fmaf(v.x, par.x, par.y), fmaf(v.y, par.x, par.z));
    }
    __syncthreads();
    // S[o][f] = scale_f * sum_i xbn[i][f] * (fkr + i*fki)[f][i][o]
    for (int i = threadIdx.x; i < F * CO; i += 256) {
        int f = i / CO, o = i - f * CO;
        float re = 0.f, im = 0.f;
        #pragma unroll
        for (int ci = 0; ci < CIN; ++ci) {
            float2 xv = xbn[ci][f];
            float kr = fkr[(f * CIN + ci) * CO + o];
            float ki = fki[(f * CIN + ci) * CO + o];
            re = fmaf(xv.x, kr, re); re = fmaf(-xv.y, ki, re);
            im = fmaf(xv.x, ki, im); im = fmaf(xv.y, kr, im);
        }
        float scale = (f == 0 || f == N / 2) ? (1.f / N) : (2.f / N);
        S[o][f] = make_float2(re * scale, im * scale);
    }
    __syncthreads();
    // fr[k] = E(k)+O(k), fr[k+N/2] = E(k)-O(k); E=even freqs (incl 0, N/2), O=odd
    constexpr int KH = N / 2;
    constexpr int OG = 256 / KH;
    int k  = threadIdx.x % KH;
    int og = threadIdx.x / KH;
    float s1, c1;
    sincosf(6.28318530717958647692f * (float)k / (float)N, &s1, &c1);
    float sgn = (k & 1) ? -1.f : 1.f;
    int l1 = t * N + k - N / 2;
    int l2 = t * N + k;
    for (int ob = 0; ob < CO; ob += OG) {
        int o = ob + og;
        const float2* Srow = S[o];
        const float4* S4   = (const float4*)Srow;
        float2 s0  = Srow[0];
        float2 snh = Srow[N / 2];
        float E  = fmaf(sgn, snh.x, s0.x);
        float cc = c1, ss = s1;            // f = 1
        float2 sf1 = Srow[1];
        float Od = fmaf(sf1.x, cc, -sf1.y * ss);
        #pragma unroll 4
        for (int j = 1; j < N / 4; ++j) {
            float4 sp = S4[j];             // (S[2j], S[2j+1])
            float cn = fmaf(cc, c1, -ss * s1); ss = fmaf(cc, s1, ss * c1); cc = cn; // f=2j
            E  = fmaf(sp.x, cc, E);  E  = fmaf(-sp.y, ss, E);
            cn = fmaf(cc, c1, -ss * s1); ss = fmaf(cc, s1, ss * c1); cc = cn;       // f=2j+1
            Od = fmaf(sp.z, cc, Od); Od = fmaf(-sp.w, ss, Od);
        }
        int ch = CH0 + o;
        float pb = pbias[ch];
        size_t obase = ((size_t)b * TCO + ch) * LL;
        float v1 = fmaxf(E + Od + pb, 0.f);
        float v2 = fmaxf(E - Od + pb, 0.f);
        if ((unsigned)l1 < LL) out[obase + l1] = v1;
        if (l2 < LL)           out[obase + l2] = v2;
    }
}

extern "C" void kernel_launch(void* const* d_in, const int* in_sizes, int n_in,
                              void* d_out, int out_size, void* d_ws, size_t ws_size,
                              hipStream_t stream) {
    const float* x     = (const float*)d_in[0];
    const float* gam   = (const float*)d_in[1];
    const float* bet   = (const float*)d_in[2];
    const float* mkr   = (const float*)d_in[3];
    const float* mki   = (const float*)d_in[4];
    const float* mbr   = (const float*)d_in[5];
    const float* mbi   = (const float*)d_in[6];
    const float* fk0r  = (const float*)d_in[7];
    const float* fk0i  = (const float*)d_in[8];
    const float* fk1r  = (const float*)d_in[9];
    const float* fk1i  = (const float*)d_in[10];
    const float* pbias = (const float*)d_in[11];
    float* out = (float*)d_out;

    float2* p0 = (float2*)d_ws;                                   // [B][128][16][33]
    float2* p1 = p0 + (size_t)BB * T0n * CIN * F0n;               // [B][32][16][129]
    float4* bn = (float4*)(p1 + (size_t)BB * T1n * CIN * F1n);    // [2][B]

    stft_kernel<64, 33, 8, 128><<<BB * CIN * 16, 256, 0, stream>>>(x, p0);
    stft_kernel<256, 129, 2, 32><<<BB * CIN * 16, 256, 0, stream>>>(x, p1);
    merge_kernel<<<(BB * T1n * CIN * F0n) / 256, 256, 0, stream>>>(p0, p1, mkr, mki, mbr, mbi);
    cbn_kernel<<<128, 256, 0, stream>>>(p0, p1, gam, bet, bn);
    istft_kernel<64, 33, 128, 0><<<BB * (T0n + 1), 256, 0, stream>>>(p0, fk0r, fk0i, bn, pbias, out);
    istft_kernel<256, 129, 32, 32><<<BB * (T1n + 1), 256, 0, stream>>>(p1, fk1r, fk1i, bn, pbias, out);
}

// Round 3
// 743.831 us; speedup vs baseline: 1.0743x; 1.0743x over previous
//
#include <hip/hip_runtime.h>
#include <math.h>

// Problem constants
#define BB   64
#define CIN  16
#define LL   8192
#define CO   32
#define TCO  64
constexpr int T0n = 128;   // frames for n=64
constexpr int T1n = 32;    // frames for n=256
constexpr int F0n = 33;
constexpr int F1n = 129;

// ---------------- STFT: real-input DFT, k<->n-k pairing, rotation recurrence ----
// p layout: [b][t][c][f] (float2 = re,im)
template<int N, int F, int TCH, int TFR>
__global__ __launch_bounds__(256)
void stft_kernel(const float* __restrict__ x, float2* __restrict__ p) {
    constexpr int NCH  = TFR / TCH;
    constexpr int SPAN = N * TCH;          // 512 for both configs
    static_assert(SPAN == 512, "span");
    __shared__ float  xs[SPAN];
    __shared__ float2 uv[TCH][N / 2];      // (u,v), k=1..N/2-1
    __shared__ float2 edge[TCH];           // (x[0], x[N/2])
    int bid   = blockIdx.x;
    int chunk = bid % NCH;
    int bc    = bid / NCH;                 // b*CIN + c
    const float* xrow = x + (size_t)bc * LL;
    int g0 = chunk * SPAN - N / 2;
    for (int i = threadIdx.x; i < SPAN; i += 256) {
        int gi = g0 + i; gi = gi < 0 ? -gi : gi;   // reflect (left edge only)
        xs[i] = xrow[gi];
    }
    __syncthreads();
    for (int i = threadIdx.x; i < TCH * (N / 2); i += 256) {
        int fl = i / (N / 2), k = i % (N / 2);
        float a = xs[fl * N + k];
        if (k == 0) {
            edge[fl] = make_float2(a, xs[fl * N + N / 2]);
        } else {
            float b2 = xs[fl * N + N - k];
            uv[fl][k] = make_float2(a + b2, a - b2);
        }
    }
    __syncthreads();
    int c = bc % CIN, b = bc / CIN;
    for (int j = threadIdx.x; j < TCH * F; j += 256) {
        int fl = j / F, f = j - fl * F;
        float2 e = edge[fl];
        float re = e.x + ((f & 1) ? -e.y : e.y);
        float im = 0.f;
        float s1, c1;
        sincosf(6.28318530717958647692f * (float)f / (float)N, &s1, &c1);
        float cc = c1, ss = s1;            // angle = 2*pi*f*k/N at k=1
        #pragma unroll 4
        for (int k = 1; k < N / 2; ++k) {
            float2 w = uv[fl][k];
            re = fmaf(w.x, cc, re);        // + u*cos
            im = fmaf(-w.y, ss, im);       // - v*sin
            float cn = fmaf(cc, c1, -ss * s1);
            ss = fmaf(cc, s1, ss * c1);
            cc = cn;
        }
        int t = chunk * TCH + fl;
        p[(((size_t)b * TFR + t) * CIN + c) * F + f] = make_float2(re, im);
    }
}

// ---------------- merge (attention over 4 sub-frames), in-place into p1 --------
__global__ __launch_bounds__(256)
void merge_kernel(const float2* __restrict__ p0, float2* __restrict__ p1,
                  const float* __restrict__ mkr, const float* __restrict__ mki,
                  const float* __restrict__ mbr, const float* __restrict__ mbi) {
    int idx = blockIdx.x * 256 + threadIdx.x;
    const int total = BB * T1n * CIN * F0n;
    if (idx >= total) return;
    int f0 = idx % F0n; int r1 = idx / F0n;
    int c  = r1 % CIN;  int r2 = r1 / CIN;
    int t1 = r2 % T1n;  int b  = r2 / T1n;
    float2 pm[4];
    #pragma unroll
    for (int r = 0; r < 4; ++r) {
        int t = t1 * 4 + r;
        pm[r] = p0[(((size_t)b * T0n + t) * CIN + c) * F0n + f0];
    }
    float mag[4], mx = -1e30f;
    #pragma unroll
    for (int s = 0; s < 4; ++s) {
        float atr = mbr[s], ati = mbi[s];
        #pragma unroll
        for (int r = 0; r < 4; ++r) {
            float kr = mkr[r * 4 + s], ki = mki[r * 4 + s];
            atr = fmaf(pm[r].x, kr, atr); atr = fmaf(-pm[r].y, ki, atr);
            ati = fmaf(pm[r].x, ki, ati); ati = fmaf(pm[r].y, kr, ati);
        }
        mag[s] = sqrtf(atr * atr + ati * ati);
        mx = fmaxf(mx, mag[s]);
    }
    float se = 0.f;
    #pragma unroll
    for (int s = 0; s < 4; ++s) { mag[s] = expf(mag[s] - mx); se += mag[s]; }
    float inv = 4.0f / se;                 // RATIO / sum
    float mr = 0.f, mi = 0.f;
    #pragma unroll
    for (int r = 0; r < 4; ++r) { mr = fmaf(pm[r].x, mag[r], mr); mi = fmaf(pm[r].y, mag[r], mi); }
    p1[(((size_t)b * T1n + t1) * CIN + c) * F1n + 4 * f0] = make_float2(mr * inv, mi * inv);
}

// ---------------- complex batch-norm stats -> per-batch affine ------------------
__global__ __launch_bounds__(256)
void cbn_kernel(const float2* __restrict__ p0, const float2* __restrict__ p1,
                const float* __restrict__ gamma, const float* __restrict__ beta,
                float4* __restrict__ bn) {
    int head = blockIdx.x >> 6;
    int b    = blockIdx.x & 63;
    int Nel  = head ? (T1n * CIN * F1n) : (T0n * CIN * F0n);
    const float2* base = head ? (p1 + (size_t)b * (T1n * CIN * F1n))
                              : (p0 + (size_t)b * (T0n * CIN * F0n));
    float sr = 0.f, si = 0.f, s2 = 0.f;
    for (int i = threadIdx.x; i < Nel; i += 256) {
        float2 v = base[i];
        sr += v.x; si += v.y;
        s2 = fmaf(v.x, v.x, s2); s2 = fmaf(v.y, v.y, s2);
    }
    __shared__ float red[3][256];
    red[0][threadIdx.x] = sr; red[1][threadIdx.x] = si; red[2][threadIdx.x] = s2;
    __syncthreads();
    for (int off = 128; off > 0; off >>= 1) {
        if (threadIdx.x < off) {
            red[0][threadIdx.x] += red[0][threadIdx.x + off];
            red[1][threadIdx.x] += red[1][threadIdx.x + off];
            red[2][threadIdx.x] += red[2][threadIdx.x + off];
        }
        __syncthreads();
    }
    if (threadIdx.x == 0) {
        float invN = 1.f / (float)Nel;
        float mur = red[0][0] * invN, mui = red[1][0] * invN;
        float var = red[2][0] * invN - mur * mur - mui * mui;
        float g = gamma[head * BB + b] * rsqrtf(var + 1e-5f);
        bn[head * BB + b] = make_float4(g, beta[head * BB + b] - mur * g, -mui * g, 0.f);
    }
}

// ---------------- fused CBN-apply + einsum + irfft + bias/relu/store -----------
// grid: B*(TFR+1); frame TFR re-uses spectrum of frame 0 (the appended wrap frame)
// S layout: [f][o within chunk] -> irfft LDS reads are wave-broadcast (conflict-free)
// irfft: 4 independent twiddle rotators (stride 4 over f), 4 outputs register-blocked
template<int N, int F, int TFR, int CH0, int OCH>
__global__ __launch_bounds__(256)
void istft_kernel(const float2* __restrict__ p, const float* __restrict__ fkr,
                  const float* __restrict__ fki, const float4* __restrict__ bn,
                  const float* __restrict__ pbias, float* __restrict__ out) {
    constexpr int KH   = N / 2;
    constexpr int NG   = 256 / KH;         // o-groups in the irfft phase
    constexpr int OBLK = OCH / NG;         // o per thread per chunk
    static_assert(OBLK == 4, "oblk");
    constexpr int OCHP = OCH + 2;          // padded row (16B aligned, <=2-way write conflicts)
    constexpr int NCHK = CO / OCH;
    __shared__ float2 xbn[CIN][F];
    __shared__ __align__(16) float2 S[F][OCHP];

    int t  = blockIdx.x % (TFR + 1);
    int b  = blockIdx.x / (TFR + 1);
    int tf = (t == TFR) ? 0 : t;
    float4 par = bn[(CH0 ? 1 : 0) * BB + b];   // (s, cb_re, cb_im, -)
    const float2* acc = p + ((size_t)b * TFR + tf) * CIN * F;
    for (int i = threadIdx.x; i < CIN * F; i += 256) {
        float2 v = acc[i];
        ((float2*)xbn)[i] = make_float2(fmaf(v.x, par.x, par.y), fmaf(v.y, par.x, par.z));
    }

    // per-thread irfft constants (k fixed across chunks)
    int k  = threadIdx.x & (KH - 1);
    int og = threadIdx.x / KH;
    float s1, c1;
    sincosf(6.28318530717958647692f * (float)k / (float)N, &s1, &c1);
    float c2 = fmaf(c1, c1, -s1 * s1), sw2 = 2.f * c1 * s1;
    float c3 = fmaf(c2, c1, -sw2 * s1), sw3 = fmaf(c2, s1, sw2 * c1);
    float C4 = fmaf(c2, c2, -sw2 * sw2), S4 = 2.f * c2 * sw2;   // advance angle 4*theta
    int l1 = t * N + k - KH;
    int l2 = t * N + k;
    size_t obase0 = (size_t)b * TCO * LL;

    __syncthreads();

    for (int chk = 0; chk < NCHK; ++chk) {
        // ---- einsum into S[f][o'] ----
        for (int i = threadIdx.x; i < F * OCH; i += 256) {
            int f = i / OCH, op = i - f * OCH;
            int o = chk * OCH + op;
            float re = 0.f, im = 0.f;
            #pragma unroll
            for (int ci = 0; ci < CIN; ++ci) {
                float2 xv = xbn[ci][f];
                float kr = fkr[(f * CIN + ci) * CO + o];
                float ki = fki[(f * CIN + ci) * CO + o];
                re = fmaf(xv.x, kr, re); re = fmaf(-xv.y, ki, re);
                im = fmaf(xv.x, ki, im); im = fmaf(xv.y, kr, im);
            }
            float scale = (f == 0 || f == KH) ? (1.f / N) : (2.f / N);
            S[f][op] = make_float2(re * scale, im * scale);
        }
        __syncthreads();

        // ---- irfft: fr[k] = E+Od, fr[k+KH] = E-Od ----
        float cr0 = 1.f, sr0 = 0.f;
        float cr1 = c1,  sr1 = s1;
        float cr2 = c2,  sr2 = sw2;
        float cr3 = c3,  sr3 = sw3;
        float E[OBLK]  = {0.f, 0.f, 0.f, 0.f};
        float Od[OBLK] = {0.f, 0.f, 0.f, 0.f};
        const char* Sbase = (const char*)&S[0][og * OBLK];
        constexpr int ROWB = OCHP * 8;     // row stride bytes
        for (int j = 0; j < N / 8; ++j) {
            const float4* r0 = (const float4*)(Sbase + (4 * j + 0) * ROWB);
            const float4* r1 = (const float4*)(Sbase + (4 * j + 1) * ROWB);
            const float4* r2 = (const float4*)(Sbase + (4 * j + 2) * ROWB);
            const float4* r3 = (const float4*)(Sbase + (4 * j + 3) * ROWB);
            float4 a0 = r0[0], b0 = r0[1];
            float4 a1 = r1[0], b1 = r1[1];
            float4 a2 = r2[0], b2 = r2[1];
            float4 a3 = r3[0], b3 = r3[1];
            // m=0 (even f) -> E
            E[0] = fmaf(a0.x, cr0, E[0]); E[0] = fmaf(-a0.y, sr0, E[0]);
            E[1] = fmaf(a0.z, cr0, E[1]); E[1] = fmaf(-a0.w, sr0, E[1]);
            E[2] = fmaf(b0.x, cr0, E[2]); E[2] = fmaf(-b0.y, sr0, E[2]);
            E[3] = fmaf(b0.z, cr0, E[3]); E[3] = fmaf(-b0.w, sr0, E[3]);
            // m=1 (odd f) -> Od
            Od[0] = fmaf(a1.x, cr1, Od[0]); Od[0] = fmaf(-a1.y, sr1, Od[0]);
            Od[1] = fmaf(a1.z, cr1, Od[1]); Od[1] = fmaf(-a1.w, sr1, Od[1]);
            Od[2] = fmaf(b1.x, cr1, Od[2]); Od[2] = fmaf(-b1.y, sr1, Od[2]);
            Od[3] = fmaf(b1.z, cr1, Od[3]); Od[3] = fmaf(-b1.w, sr1, Od[3]);
            // m=2 (even f) -> E
            E[0] = fmaf(a2.x, cr2, E[0]); E[0] = fmaf(-a2.y, sr2, E[0]);
            E[1] = fmaf(a2.z, cr2, E[1]); E[1] = fmaf(-a2.w, sr2, E[1]);
            E[2] = fmaf(b2.x, cr2, E[2]); E[2] = fmaf(-b2.y, sr2, E[2]);
            E[3] = fmaf(b2.z, cr2, E[3]); E[3] = fmaf(-b2.w, sr2, E[3]);
            // m=3 (odd f) -> Od
            Od[0] = fmaf(a3.x, cr3, Od[0]); Od[0] = fmaf(-a3.y, sr3, Od[0]);
            Od[1] = fmaf(a3.z, cr3, Od[1]); Od[1] = fmaf(-a3.w, sr3, Od[1]);
            Od[2] = fmaf(b3.x, cr3, Od[2]); Od[2] = fmaf(-b3.y, sr3, Od[2]);
            Od[3] = fmaf(b3.z, cr3, Od[3]); Od[3] = fmaf(-b3.w, sr3, Od[3]);
            // advance 4 rotators by 4*theta (independent chains)
            float cn;
            cn = fmaf(cr0, C4, -sr0 * S4); sr0 = fmaf(cr0, S4, sr0 * C4); cr0 = cn;
            cn = fmaf(cr1, C4, -sr1 * S4); sr1 = fmaf(cr1, S4, sr1 * C4); cr1 = cn;
            cn = fmaf(cr2, C4, -sr2 * S4); sr2 = fmaf(cr2, S4, sr2 * C4); cr2 = cn;
            cn = fmaf(cr3, C4, -sr3 * S4); sr3 = fmaf(cr3, S4, sr3 * C4); cr3 = cn;
        }
        {   // Nyquist f = KH via rotator 0 (now at angle KH*theta)
            const float4* rn = (const float4*)(Sbase + KH * ROWB);
            float4 an = rn[0], bnq = rn[1];
            E[0] = fmaf(an.x, cr0, E[0]); E[0] = fmaf(-an.y, sr0, E[0]);
            E[1] = fmaf(an.z, cr0, E[1]); E[1] = fmaf(-an.w, sr0, E[1]);
            E[2] = fmaf(bnq.x, cr0, E[2]); E[2] = fmaf(-bnq.y, sr0, E[2]);
            E[3] = fmaf(bnq.z, cr0, E[3]); E[3] = fmaf(-bnq.w, sr0, E[3]);
        }
        #pragma unroll
        for (int oo = 0; oo < OBLK; ++oo) {
            int ch = CH0 + chk * OCH + og * OBLK + oo;
            float pb = pbias[ch];
            size_t obase = obase0 + (size_t)ch * LL;
            float v1 = fmaxf(E[oo] + Od[oo] + pb, 0.f);
            float v2 = fmaxf(E[oo] - Od[oo] + pb, 0.f);
            if ((unsigned)l1 < LL) out[obase + l1] = v1;
            if (l2 < LL)           out[obase + l2] = v2;
        }
        __syncthreads();
    }
}

extern "C" void kernel_launch(void* const* d_in, const int* in_sizes, int n_in,
                              void* d_out, int out_size, void* d_ws, size_t ws_size,
                              hipStream_t stream) {
    const float* x     = (const float*)d_in[0];
    const float* gam   = (const float*)d_in[1];
    const float* bet   = (const float*)d_in[2];
    const float* mkr   = (const float*)d_in[3];
    const float* mki   = (const float*)d_in[4];
    const float* mbr   = (const float*)d_in[5];
    const float* mbi   = (const float*)d_in[6];
    const float* fk0r  = (const float*)d_in[7];
    const float* fk0i  = (const float*)d_in[8];
    const float* fk1r  = (const float*)d_in[9];
    const float* fk1i  = (const float*)d_in[10];
    const float* pbias = (const float*)d_in[11];
    float* out = (float*)d_out;

    float2* p0 = (float2*)d_ws;                                   // [B][128][16][33]
    float2* p1 = p0 + (size_t)BB * T0n * CIN * F0n;               // [B][32][16][129]
    float4* bn = (float4*)(p1 + (size_t)BB * T1n * CIN * F1n);    // [2][B]

    stft_kernel<64, 33, 8, 128><<<BB * CIN * 16, 256, 0, stream>>>(x, p0);
    stft_kernel<256, 129, 2, 32><<<BB * CIN * 16, 256, 0, stream>>>(x, p1);
    merge_kernel<<<(BB * T1n * CIN * F0n) / 256, 256, 0, stream>>>(p0, p1, mkr, mki, mbr, mbi);
    cbn_kernel<<<128, 256, 0, stream>>>(p0, p1, gam, bet, bn);
    istft_kernel<64, 33, 128, 0, 32><<<BB * (T0n + 1), 256, 0, stream>>>(p0, fk0r, fk0i, bn, pbias, out);
    istft_kernel<256, 129, 32, 32, 8><<<BB * (T1n + 1), 256, 0, stream>>>(p1, fk1r, fk1i, bn, pbias, out);
}

// Round 6
// 701.070 us; speedup vs baseline: 1.1398x; 1.0610x over previous
//
#include <hip/hip_runtime.h>
#include <math.h>

// Problem constants
#define BB   64
#define CIN  16
#define LL   8192
#define CO   32
#define TCO  64
constexpr int T0n = 128;   // frames for n=64
constexpr int T1n = 32;    // frames for n=256
constexpr int F0n = 33;
constexpr int F1n = 129;

typedef unsigned int   uint32;
typedef unsigned short u16;
typedef __attribute__((ext_vector_type(8))) _Float16 half8;  // 8 f16 (4 VGPRs)
typedef __attribute__((ext_vector_type(4))) float    f32x4;  // MFMA accumulator

// ---------------- STFT: real-input DFT, k<->n-k pairing, rotation recurrence ----
// p layout: [b][t][c][f] (float2 = re,im)
template<int N, int F, int TCH, int TFR>
__global__ __launch_bounds__(256)
void stft_kernel(const float* __restrict__ x, float2* __restrict__ p) {
    constexpr int NCH  = TFR / TCH;
    constexpr int SPAN = N * TCH;          // 512 for both configs
    static_assert(SPAN == 512, "span");
    __shared__ float  xs[SPAN];
    __shared__ float2 uv[TCH][N / 2];      // (u,v), k=1..N/2-1
    __shared__ float2 edge[TCH];           // (x[0], x[N/2])
    int bid   = blockIdx.x;
    int chunk = bid % NCH;
    int bc    = bid / NCH;                 // b*CIN + c
    const float* xrow = x + (size_t)bc * LL;
    int g0 = chunk * SPAN - N / 2;
    for (int i = threadIdx.x; i < SPAN; i += 256) {
        int gi = g0 + i; gi = gi < 0 ? -gi : gi;   // reflect (left edge only)
        xs[i] = xrow[gi];
    }
    __syncthreads();
    for (int i = threadIdx.x; i < TCH * (N / 2); i += 256) {
        int fl = i / (N / 2), k = i % (N / 2);
        float a = xs[fl * N + k];
        if (k == 0) {
            edge[fl] = make_float2(a, xs[fl * N + N / 2]);
        } else {
            float b2 = xs[fl * N + N - k];
            uv[fl][k] = make_float2(a + b2, a - b2);
        }
    }
    __syncthreads();
    int c = bc % CIN, b = bc / CIN;
    for (int j = threadIdx.x; j < TCH * F; j += 256) {
        int fl = j / F, f = j - fl * F;
        float2 e = edge[fl];
        float re = e.x + ((f & 1) ? -e.y : e.y);
        float im = 0.f;
        float s1, c1;
        sincosf(6.28318530717958647692f * (float)f / (float)N, &s1, &c1);
        float cc = c1, ss = s1;            // angle = 2*pi*f*k/N at k=1
        #pragma unroll 4
        for (int k = 1; k < N / 2; ++k) {
            float2 w = uv[fl][k];
            re = fmaf(w.x, cc, re);        // + u*cos
            im = fmaf(-w.y, ss, im);       // - v*sin
            float cn = fmaf(cc, c1, -ss * s1);
            ss = fmaf(cc, s1, ss * c1);
            cc = cn;
        }
        int t = chunk * TCH + fl;
        p[(((size_t)b * TFR + t) * CIN + c) * F + f] = make_float2(re, im);
    }
}

// ---------------- merge (attention over 4 sub-frames), in-place into p1 --------
__global__ __launch_bounds__(256)
void merge_kernel(const float2* __restrict__ p0, float2* __restrict__ p1,
                  const float* __restrict__ mkr, const float* __restrict__ mki,
                  const float* __restrict__ mbr, const float* __restrict__ mbi) {
    int idx = blockIdx.x * 256 + threadIdx.x;
    const int total = BB * T1n * CIN * F0n;
    if (idx >= total) return;
    int f0 = idx % F0n; int r1 = idx / F0n;
    int c  = r1 % CIN;  int r2 = r1 / CIN;
    int t1 = r2 % T1n;  int b  = r2 / T1n;
    float2 pm[4];
    #pragma unroll
    for (int r = 0; r < 4; ++r) {
        int t = t1 * 4 + r;
        pm[r] = p0[(((size_t)b * T0n + t) * CIN + c) * F0n + f0];
    }
    float mag[4], mx = -1e30f;
    #pragma unroll
    for (int s = 0; s < 4; ++s) {
        float atr = mbr[s], ati = mbi[s];
        #pragma unroll
        for (int r = 0; r < 4; ++r) {
            float kr = mkr[r * 4 + s], ki = mki[r * 4 + s];
            atr = fmaf(pm[r].x, kr, atr); atr = fmaf(-pm[r].y, ki, atr);
            ati = fmaf(pm[r].x, ki, ati); ati = fmaf(pm[r].y, kr, ati);
        }
        mag[s] = sqrtf(atr * atr + ati * ati);
        mx = fmaxf(mx, mag[s]);
    }
    float se = 0.f;
    #pragma unroll
    for (int s = 0; s < 4; ++s) { mag[s] = expf(mag[s] - mx); se += mag[s]; }
    float inv = 4.0f / se;                 // RATIO / sum
    float mr = 0.f, mi = 0.f;
    #pragma unroll
    for (int r = 0; r < 4; ++r) { mr = fmaf(pm[r].x, mag[r], mr); mi = fmaf(pm[r].y, mag[r], mi); }
    p1[(((size_t)b * T1n + t1) * CIN + c) * F1n + 4 * f0] = make_float2(mr * inv, mi * inv);
}

// ---------------- complex batch-norm stats -> per-batch affine ------------------
__global__ __launch_bounds__(256)
void cbn_kernel(const float2* __restrict__ p0, const float2* __restrict__ p1,
                const float* __restrict__ gamma, const float* __restrict__ beta,
                float4* __restrict__ bn) {
    int head = blockIdx.x >> 6;
    int b    = blockIdx.x & 63;
    int Nel  = head ? (T1n * CIN * F1n) : (T0n * CIN * F0n);
    const float2* base = head ? (p1 + (size_t)b * (T1n * CIN * F1n))
                              : (p0 + (size_t)b * (T0n * CIN * F0n));
    float sr = 0.f, si = 0.f, s2 = 0.f;
    for (int i = threadIdx.x; i < Nel; i += 256) {
        float2 v = base[i];
        sr += v.x; si += v.y;
        s2 = fmaf(v.x, v.x, s2); s2 = fmaf(v.y, v.y, s2);
    }
    __shared__ float red[3][256];
    red[0][threadIdx.x] = sr; red[1][threadIdx.x] = si; red[2][threadIdx.x] = s2;
    __syncthreads();
    for (int off = 128; off > 0; off >>= 1) {
        if (threadIdx.x < off) {
            red[0][threadIdx.x] += red[0][threadIdx.x + off];
            red[1][threadIdx.x] += red[1][threadIdx.x + off];
            red[2][threadIdx.x] += red[2][threadIdx.x + off];
        }
        __syncthreads();
    }
    if (threadIdx.x == 0) {
        float invN = 1.f / (float)Nel;
        float mur = red[0][0] * invN, mui = red[1][0] * invN;
        float var = red[2][0] * invN - mur * mur - mui * mui;
        float g = gamma[head * BB + b] * rsqrtf(var + 1e-5f);
        bn[head * BB + b] = make_float4(g, beta[head * BB + b] - mur * g, -mui * g, 0.f);
    }
}

// ---------------- init: irfft twiddle matrix, A-fragment order, split fp16 -----
// W[m][k2]: k2=2f -> scale_f*cos(2*pi*m*f/N); k2=2f+1 -> -scale_f*sin(...)
// W scaled by 2^10; S scaled by 2^5; epilogue multiplies by 2^-15.
// frag idx = ((mtile*KT + kt)*64 + lane)*8 + j ; m = mtile*16+(lane&15),
// k2 = kt*32 + (lane>>4)*8 + j.  sin(0)=0 zeroes DC/Nyquist imag (numpy irfft).
__global__ __launch_bounds__(256)
void init_w_kernel(u16* __restrict__ whi0, u16* __restrict__ wlo0,
                   u16* __restrict__ whi1, u16* __restrict__ wlo1) {
    int idx = blockIdx.x * 256 + threadIdx.x;
    int N, F, KT, id; u16 *dh, *dl;
    if (idx < 6144)              { N = 64;  F = F0n; KT = 3; dh = whi0; dl = wlo0; id = idx; }
    else if (idx < 6144 + 73728) { N = 256; F = F1n; KT = 9; dh = whi1; dl = wlo1; id = idx - 6144; }
    else return;
    int j    = id & 7;
    int lane = (id >> 3) & 63;
    int rest = id >> 9;
    int kt   = rest % KT;
    int mt   = rest / KT;
    int m  = mt * 16 + (lane & 15);
    int k2 = kt * 32 + (lane >> 4) * 8 + j;
    float v = 0.f;
    if (k2 < 2 * F) {
        int f = k2 >> 1;
        double scale = (f == 0 || f == F - 1) ? (1024.0 / N) : (2048.0 / N);
        int u = (m * f) % N;
        double th = 6.283185307179586476925286766559 * (double)u / (double)N;
        v = (float)((k2 & 1) ? (-scale * sin(th)) : (scale * cos(th)));
    }
    _Float16 h = (_Float16)v;
    _Float16 l = (_Float16)(v - (float)h);
    dh[id] = *(u16*)&h;
    dl[id] = *(u16*)&l;
}

// ---------------- init: fk tables repacked [f][o][ci] float2 (fp32) -------------
__global__ __launch_bounds__(256)
void init_fk_kernel(const float* __restrict__ r0, const float* __restrict__ i0,
                    const float* __restrict__ r1, const float* __restrict__ i1,
                    float2* __restrict__ d0, float2* __restrict__ d1) {
    int idx = blockIdx.x * 256 + threadIdx.x;
    const float *r, *im; float2* dst; int id;
    if (idx < F0n * 512)               { r = r0; im = i0; dst = d0; id = idx; }
    else if (idx < (F0n + F1n) * 512)  { r = r1; im = i1; dst = d1; id = idx - F0n * 512; }
    else return;
    int f   = id >> 9;
    int rem = id & 511;
    int o   = rem >> 4;
    int ci  = rem & 15;
    int s = (f * CIN + ci) * CO + o;
    dst[id] = make_float2(r[s], im[s]);
}

// ---------------- fused CBN-apply + einsum(fp32) + irfft(split-fp16 MFMA) ------
// grid: B*(TFR+1); frame TFR re-uses spectrum of frame 0 (wrap frame)
template<int N, int F, int TFR, int CH0, int KT, int KPAD>
__global__ __launch_bounds__(256)
void istft_kernel(const float2* __restrict__ p,
                  const u16* __restrict__ whi, const u16* __restrict__ wlo,
                  const float2* __restrict__ fkb, const float4* __restrict__ bn,
                  const float* __restrict__ pbias, float* __restrict__ out) {
    constexpr int MTW = N / 64;            // M-tiles per wave (1 or 4)
    __shared__ float2 xbn[F][18];          // [f][ci], pad->conflict-free writes
    __shared__ u16 Shi[32][KPAD];          // [o][k2] f16 hi (x32 scale)
    __shared__ u16 Slo[32][KPAD];          // [o][k2] f16 lo (residual)

    int t  = blockIdx.x % (TFR + 1);
    int b  = blockIdx.x / (TFR + 1);
    int tf = (t == TFR) ? 0 : t;
    float4 par = bn[(CH0 ? 1 : 0) * BB + b];   // (s, cb_re, cb_im, -)
    const float2* acc = p + ((size_t)b * TFR + tf) * CIN * F;
    for (int i = threadIdx.x; i < CIN * F; i += 256) {
        int ci = i / F, f = i - ci * F;
        float2 v = acc[i];
        xbn[f][ci] = make_float2(fmaf(v.x, par.x, par.y), fmaf(v.y, par.x, par.z));
    }
    __syncthreads();

    // einsum (fp32): S[o][2f]=re*32, S[o][2f+1]=im*32 (1/N etc folded into W)
    for (int i = threadIdx.x; i < F * CO; i += 256) {
        int f = i >> 5, o = i & 31;
        const float4* kk4 = (const float4*)(fkb + (size_t)i * 16);  // 8x (kr,ki,kr,ki)
        const float4* xv4 = (const float4*)&xbn[f][0];              // 8x (xr,xi,xr,xi)
        float re = 0.f, im = 0.f;
        #pragma unroll
        for (int q = 0; q < 8; ++q) {
            float4 kk = kk4[q];
            float4 xx = xv4[q];
            re = fmaf(xx.x, kk.x, re); re = fmaf(-xx.y, kk.y, re);
            im = fmaf(xx.x, kk.y, im); im = fmaf(xx.y, kk.x, im);
            re = fmaf(xx.z, kk.z, re); re = fmaf(-xx.w, kk.w, re);
            im = fmaf(xx.z, kk.w, im); im = fmaf(xx.w, kk.z, im);
        }
        float res = re * 32.f, ims = im * 32.f;
        _Float16 rh = (_Float16)res; _Float16 rl = (_Float16)(res - (float)rh);
        _Float16 ih = (_Float16)ims; _Float16 il = (_Float16)(ims - (float)ih);
        ((uint32*)&Shi[o][0])[f] = ((uint32)(*(u16*)&ih) << 16) | (uint32)(*(u16*)&rh);
        ((uint32*)&Slo[o][0])[f] = ((uint32)(*(u16*)&il) << 16) | (uint32)(*(u16*)&rl);
    }
    // zero-pad K region [F, KT*16) dwords in both arrays
    for (int i = threadIdx.x; i < 32 * (KT * 16 - F); i += 256) {
        constexpr int cols = KT * 16 - F;
        int o = i / cols, j = i - o * cols;
        ((uint32*)&Shi[o][0])[F + j] = 0;
        ((uint32*)&Slo[o][0])[F + j] = 0;
    }
    __syncthreads();

    // MFMA: out[k][ch] = sum_k2 W[k][k2]*S[k2][ch],  W*S ~ Wh*Sh + Wh*Sl + Wl*Sh
    int lane = threadIdx.x & 63, wave = threadIdx.x >> 6;
    int col = lane & 15, quad = lane >> 4;
    f32x4 accv[MTW][2];
    #pragma unroll
    for (int mt = 0; mt < MTW; ++mt)
        #pragma unroll
        for (int nt = 0; nt < 2; ++nt) {
            f32x4 z = {0.f, 0.f, 0.f, 0.f};
            accv[mt][nt] = z;
        }
    for (int kt = 0; kt < KT; ++kt) {
        half8 bh0 = *(const half8*)&Shi[col][kt * 32 + quad * 8];
        half8 bh1 = *(const half8*)&Shi[16 + col][kt * 32 + quad * 8];
        half8 bl0 = *(const half8*)&Slo[col][kt * 32 + quad * 8];
        half8 bl1 = *(const half8*)&Slo[16 + col][kt * 32 + quad * 8];
        #pragma unroll
        for (int mt = 0; mt < MTW; ++mt) {
            int mtile = wave * MTW + mt;
            half8 ah = ((const half8*)whi)[(mtile * KT + kt) * 64 + lane];
            half8 al = ((const half8*)wlo)[(mtile * KT + kt) * 64 + lane];
            accv[mt][0] = __builtin_amdgcn_mfma_f32_16x16x32_f16(ah, bh0, accv[mt][0], 0, 0, 0);
            accv[mt][0] = __builtin_amdgcn_mfma_f32_16x16x32_f16(ah, bl0, accv[mt][0], 0, 0, 0);
            accv[mt][0] = __builtin_amdgcn_mfma_f32_16x16x32_f16(al, bh0, accv[mt][0], 0, 0, 0);
            accv[mt][1] = __builtin_amdgcn_mfma_f32_16x16x32_f16(ah, bh1, accv[mt][1], 0, 0, 0);
            accv[mt][1] = __builtin_amdgcn_mfma_f32_16x16x32_f16(ah, bl1, accv[mt][1], 0, 0, 0);
            accv[mt][1] = __builtin_amdgcn_mfma_f32_16x16x32_f16(al, bh1, accv[mt][1], 0, 0, 0);
        }
    }
    // epilogue: row = quad*4+reg (4 consecutive l), col = ch within ntile
    constexpr float UNSCALE = 1.0f / 32768.0f;   // 2^-15 (W*2^10, S*2^5)
    size_t bb = (size_t)b * TCO;
    #pragma unroll
    for (int mt = 0; mt < MTW; ++mt) {
        int l0 = t * N + (wave * MTW + mt) * 16 + quad * 4 - N / 2;
        if ((unsigned)l0 < LL) {
            #pragma unroll
            for (int nt = 0; nt < 2; ++nt) {
                int ch = CH0 + nt * 16 + col;
                float pb = pbias[ch];
                f32x4 a = accv[mt][nt];
                float4 v;
                v.x = fmaxf(fmaf(a[0], UNSCALE, pb), 0.f);
                v.y = fmaxf(fmaf(a[1], UNSCALE, pb), 0.f);
                v.z = fmaxf(fmaf(a[2], UNSCALE, pb), 0.f);
                v.w = fmaxf(fmaf(a[3], UNSCALE, pb), 0.f);
                *(float4*)(out + (bb + ch) * LL + l0) = v;
            }
        }
    }
}

extern "C" void kernel_launch(void* const* d_in, const int* in_sizes, int n_in,
                              void* d_out, int out_size, void* d_ws, size_t ws_size,
                              hipStream_t stream) {
    const float* x     = (const float*)d_in[0];
    const float* gam   = (const float*)d_in[1];
    const float* bet   = (const float*)d_in[2];
    const float* mkr   = (const float*)d_in[3];
    const float* mki   = (const float*)d_in[4];
    const float* mbr   = (const float*)d_in[5];
    const float* mbi   = (const float*)d_in[6];
    const float* fk0r  = (const float*)d_in[7];
    const float* fk0i  = (const float*)d_in[8];
    const float* fk1r  = (const float*)d_in[9];
    const float* fk1i  = (const float*)d_in[10];
    const float* pbias = (const float*)d_in[11];
    float* out = (float*)d_out;

    float2* p0   = (float2*)d_ws;                                   // 34.6 MB
    float2* p1   = p0 + (size_t)BB * T0n * CIN * F0n;               // 33.8 MB
    float4* bnp  = (float4*)(p1 + (size_t)BB * T1n * CIN * F1n);    // 2 KB
    u16*    whi0 = (u16*)(bnp + 2 * BB);                            // 12 KB
    u16*    wlo0 = whi0 + 6144;
    u16*    whi1 = wlo0 + 6144;                                     // 144 KB
    u16*    wlo1 = whi1 + 73728;
    float2* fkb0 = (float2*)(wlo1 + 73728);                         // 132 KB
    float2* fkb1 = fkb0 + F0n * 512;                                // 516 KB

    init_w_kernel<<<(6144 + 73728 + 255) / 256, 256, 0, stream>>>(whi0, wlo0, whi1, wlo1);
    init_fk_kernel<<<((F0n + F1n) * 512 + 255) / 256, 256, 0, stream>>>(
        fk0r, fk0i, fk1r, fk1i, fkb0, fkb1);
    stft_kernel<64, 33, 8, 128><<<BB * CIN * 16, 256, 0, stream>>>(x, p0);
    stft_kernel<256, 129, 2, 32><<<BB * CIN * 16, 256, 0, stream>>>(x, p1);
    merge_kernel<<<(BB * T1n * CIN * F0n) / 256, 256, 0, stream>>>(p0, p1, mkr, mki, mbr, mbi);
    cbn_kernel<<<128, 256, 0, stream>>>(p0, p1, gam, bet, bnp);
    istft_kernel<64, 33, 128, 0, 3, 104><<<BB * (T0n + 1), 256, 0, stream>>>(
        p0, whi0, wlo0, fkb0, bnp, pbias, out);
    istft_kernel<256, 129, 32, 32, 9, 296><<<BB * (T1n + 1), 256, 0, stream>>>(
        p1, whi1, wlo1, fkb1, bnp, pbias, out);
}